// Round 3
// baseline (243.407 us; speedup 1.0000x reference)
//
#include <hip/hip_runtime.h>

#define LQ 4096
#define CH 128
#define NB 4
// log2(e)/sqrt(128): folded into Q so softmax = exp2(S)
#define QSCALE 0.12753139626233174f
#define MAXCH 8
#define TILE_HW 8192   // one 64-key tile in fragment-slot order: 16 KB = 8192 ushort

typedef __attribute__((ext_vector_type(8))) unsigned short ushort8;
typedef __attribute__((ext_vector_type(4))) unsigned short ushort4v;
typedef __attribute__((ext_vector_type(8))) __bf16 bf16x8;
typedef __attribute__((ext_vector_type(4))) float f32x4;

__device__ inline unsigned short f2bf(float f) {
    unsigned int u = __builtin_bit_cast(unsigned int, f);
    u += 0x7fffu + ((u >> 16) & 1u);   // round-to-nearest-even
    return (unsigned short)(u >> 16);
}
__device__ inline float bf2f(unsigned short h) {
    unsigned int u = (unsigned int)h << 16;
    return __builtin_bit_cast(float, u);
}
// pack two positive floats to bf16 pair, round-half-up
__device__ inline unsigned int bfpack2(float a, float b) {
    unsigned int ua = __builtin_bit_cast(unsigned int, a) + 0x8000u;
    unsigned int ub = __builtin_bit_cast(unsigned int, b) + 0x8000u;
    return (ua >> 16) | (ub & 0xffff0000u);
}
// async 16B/lane global->LDS DMA: dest = lds_base + lane*16 (wave-uniform base)
__device__ inline void gload_lds16(const unsigned short* g, unsigned short* l) {
    __builtin_amdgcn_global_load_lds(
        (const __attribute__((address_space(1))) unsigned int*)(g),
        (__attribute__((address_space(3))) unsigned int*)(l), 16, 0, 0);
}

// ---------------------------------------------------------------------------
// Kernel 1: v = W_kv @ x (+bias), MFMA; emit Vt2/Vc2 in FRAGMENT-SLOT order
// (64-key tiles):
//   Vt2[b][T][g=nt*4+kc][lane=quad*16+l16] (16B) = V[t=64T+16nt+l16][c=32kc+8quad..+8]
//   Vc2[b][T][g=a*8+nc ][lane]             (16B):
//       element j = V[t = 32a + 16*(j>>2) + 4*quad + (j&3)][c = nc*16 + l16]
//   (k-permuted K=32 B-operand for PV: k-slot quad*8+j <-> t as above, matching
//    the S^T lane layout so P needs NO cross-lane shuffle to become the A-frag)
// ---------------------------------------------------------------------------
__global__ __launch_bounds__(256) void prep_kernel(
    const float* __restrict__ x, const float* __restrict__ Wkv,
    const float* __restrict__ bkv,
    unsigned short* __restrict__ Vt2, unsigned short* __restrict__ Vc2)
{
    __shared__ __align__(16) unsigned short xs[64 * 136];  // [l][c] bf16
    __shared__ __align__(16) unsigned short vs[128 * 72];  // [o][l] bf16
    const int tid = threadIdx.x;
    const int lane = tid & 63;
    const int wave = tid >> 6;
    const int quad = lane >> 4, l16 = lane & 15;
    const int b = blockIdx.x & 3;
    const int T = blockIdx.x >> 2;
    const int l0 = T << 6;

    {   // stage x tile transposed: [64 l][128 c] bf16 (coalesced f32x4 loads)
        const f32x4* xg4 = (const f32x4*)(x + (size_t)b * CH * LQ + l0);
        #pragma unroll
        for (int i = 0; i < 8; ++i) {
            int idx = i * 256 + tid;          // 2048 chunks: c(128) x l4(16)
            int c = idx >> 4, l4 = idx & 15;
            f32x4 v = xg4[c * (LQ / 4) + l4];
            #pragma unroll
            for (int m = 0; m < 4; ++m) xs[(l4 * 4 + m) * 136 + c] = f2bf(v[m]);
        }
    }
    __syncthreads();

    const int wo = wave * 32;
    f32x4 acc[2][4];   // [ot][lt]
    #pragma unroll
    for (int ot = 0; ot < 2; ++ot)
        #pragma unroll
        for (int lt = 0; lt < 4; ++lt) acc[ot][lt] = f32x4{0.f, 0.f, 0.f, 0.f};

    #pragma unroll
    for (int kc = 0; kc < 4; ++kc) {
        bf16x8 af[2];
        #pragma unroll
        for (int ot = 0; ot < 2; ++ot) {
            const float* wrow = Wkv + (size_t)(wo + ot * 16 + l16) * CH + kc * 32 + quad * 8;
            f32x4 w0 = *(const f32x4*)(wrow);
            f32x4 w1 = *(const f32x4*)(wrow + 4);
            ushort8 a;
            #pragma unroll
            for (int j = 0; j < 4; ++j) { a[j] = f2bf(w0[j]); a[j + 4] = f2bf(w1[j]); }
            af[ot] = __builtin_bit_cast(bf16x8, a);
        }
        #pragma unroll
        for (int lt = 0; lt < 4; ++lt) {
            bf16x8 bf = __builtin_bit_cast(bf16x8,
                *(const ushort8*)(xs + (lt * 16 + l16) * 136 + kc * 32 + quad * 8));
            #pragma unroll
            for (int ot = 0; ot < 2; ++ot)
                acc[ot][lt] = __builtin_amdgcn_mfma_f32_16x16x32_bf16(af[ot], bf, acc[ot][lt], 0, 0, 0);
        }
    }
    // bias + stage to vs[o][l] (C-layout: o = wo+ot*16+quad*4+r, l = lt*16+l16)
    #pragma unroll
    for (int ot = 0; ot < 2; ++ot) {
        float bias[4];
        #pragma unroll
        for (int r = 0; r < 4; ++r) bias[r] = bkv[wo + ot * 16 + quad * 4 + r];
        #pragma unroll
        for (int lt = 0; lt < 4; ++lt)
            #pragma unroll
            for (int r = 0; r < 4; ++r)
                vs[(wo + ot * 16 + quad * 4 + r) * 72 + lt * 16 + l16] =
                    f2bf(acc[ot][lt][r] + bias[r]);
    }
    __syncthreads();
    const size_t tbase = ((size_t)b * 64 + T) * TILE_HW;
    // Vt2: 1024 16B-chunks, 4/thread, consecutive tid -> consecutive 16B (coalesced)
    #pragma unroll
    for (int i = 0; i < 4; ++i) {
        const int ci = i * 256 + tid;
        const int g = ci >> 6, ls = ci & 63;
        const int nt = g >> 2, kc = g & 3, qs = ls >> 4, l16s = ls & 15;
        ushort8 v;
        #pragma unroll
        for (int j = 0; j < 8; ++j) v[j] = vs[(kc * 32 + qs * 8 + j) * 72 + nt * 16 + l16s];
        *(ushort8*)(Vt2 + tbase + (size_t)ci * 8) = v;
    }
    // Vc2: 1024 16B-chunks, K=32 k-permuted layout (see header comment)
    #pragma unroll
    for (int i = 0; i < 4; ++i) {
        const int ci = i * 256 + tid;
        const int g = ci >> 6, ls = ci & 63;
        const int a = g >> 3, nc = g & 7, qs = ls >> 4, l16s = ls & 15;
        const int base = (nc * 16 + l16s) * 72 + a * 32 + qs * 4;
        ushort4v lo4 = *(const ushort4v*)(vs + base);        // t = 32a+4q+0..3
        ushort4v hi4 = *(const ushort4v*)(vs + base + 16);   // t = 32a+16+4q+0..3
        ushort8 v;
        #pragma unroll
        for (int j = 0; j < 4; ++j) { v[j] = lo4[j]; v[j + 4] = hi4[j]; }
        *(ushort8*)(Vc2 + tbase + (size_t)ci * 8) = v;
    }
}

// ---------------------------------------------------------------------------
// Kernel 2: flash attention, split-K. r12 structure:
//   - 64-key tiles, SINGLE-buffered bufA/bufB (32 KB LDS), 3 barriers/iter:
//       [vmcnt0+bar] issueB -> QK(a=0) -> [vmcnt0+bar] PV(a=0) -> QK(a=1)
//       -> [lgkm0+bar] issueA(it+1) -> PV(a=1)
//     Each buffer overwrite is barrier-fenced from all cross-wave readers;
//     only one tensor is in flight at each vmcnt(0) so nothing over-drains.
//   - Sub-phase split keeps only pk[2][4] (8 VGPR) of P live -> with
//     launch_bounds(256,4) total regs <= 128 (64 VGPR + 64 AGPR oacc)
//     -> 4 waves/SIMD (granule-64 alloc: r10 proved 128 total -> 4 waves).
//   - PV uses 16x16x32 MFMA with k-permuted Vc2 (prep header): 32 MFMAs/iter
//     instead of 64 16x16x16 -> PV matrix-pipe time halves.
// Every LDS read is ds_read_b128 at group_base + lane*16 (conflict-free).
// ---------------------------------------------------------------------------
__global__ __launch_bounds__(256, 4) void attn_kernel(
    const float* __restrict__ x, const unsigned short* __restrict__ Vt2,
    const unsigned short* __restrict__ Vc2,
    unsigned short* __restrict__ Opart, float* __restrict__ Lsum, int titers)
{
    __shared__ __align__(16) unsigned short bufA[TILE_HW];  // Vt tile, 16 KB
    __shared__ __align__(16) unsigned short bufB[TILE_HW];  // Vc tile, 16 KB
    const int tid = threadIdx.x;
    const int wave = tid >> 6, lane = tid & 63;
    const int quad = lane >> 4, l16 = lane & 15;
    const int b = blockIdx.x & 3;
    const int rest = blockIdx.x >> 2;
    const int qtile = rest & 31;           // 32 tiles of 128 q
    const int chunk = rest >> 5;           // nchunk split-K chunks
    const int q0w = (qtile << 7) + (wave << 5);
    const int Tbase = chunk * titers;

    const unsigned short* vtb = Vt2 + (size_t)b * 64 * TILE_HW;
    const unsigned short* vcb = Vc2 + (size_t)b * 64 * TILE_HW;

    // DMA issue: wave w stages groups w*4..w*4+3 of one tensor (4 instr/wave)
    auto issueA = [&](int T) {
        const unsigned short* sa = vtb + (size_t)T * TILE_HW + lane * 8;
        #pragma unroll
        for (int g = 0; g < 4; ++g) {
            const int go = (wave * 4 + g) * 512;
            gload_lds16(sa + go, &bufA[go]);
        }
    };
    auto issueB = [&](int T) {
        const unsigned short* sb = vcb + (size_t)T * TILE_HW + lane * 8;
        #pragma unroll
        for (int g = 0; g < 4; ++g) {
            const int go = (wave * 4 + g) * 512;
            gload_lds16(sb + go, &bufB[go]);
        }
    };
    issueA(Tbase);   // in flight under the Q prologue

    // Q B-frags from x: B[n=l16 -> q][k=quad*8+j -> c], scaled (one-time)
    bf16x8 qf[2][4];
    #pragma unroll
    for (int mt = 0; mt < 2; ++mt)
        #pragma unroll
        for (int kc = 0; kc < 4; ++kc) {
            ushort8 v;
            #pragma unroll
            for (int j = 0; j < 8; ++j) {
                int c = kc * 32 + quad * 8 + j;
                v[j] = f2bf(x[((size_t)b * CH + c) * LQ + q0w + mt * 16 + l16] * QSCALE);
            }
            qf[mt][kc] = __builtin_bit_cast(bf16x8, v);
        }

    f32x4 oacc[2][8];
    #pragma unroll
    for (int mt = 0; mt < 2; ++mt)
        #pragma unroll
        for (int i = 0; i < 8; ++i) oacc[mt][i] = f32x4{0.f, 0.f, 0.f, 0.f};
    float lsum[2] = {0.f, 0.f};

    for (int it = 0; it < titers; ++it) {
        // ---- barrier A: Vt(it) landed; prior PV(a=1) bufB reads done ----
        asm volatile("s_waitcnt vmcnt(0)" ::: "memory");
        __builtin_amdgcn_s_barrier();
        issueB(Tbase + it);        // Vc(it): QK(a=0) phase to land

        unsigned int pk[2][4];     // P as K=32 A-frag words (8 VGPR)

        #pragma unroll
        for (int a = 0; a < 2; ++a) {
            // ---- QK sub-phase: nt = 2a, 2a+1 -> pk ----
            #pragma unroll
            for (int h = 0; h < 2; ++h) {
                const int nt = a * 2 + h;
                f32x4 s0 = f32x4{0.f, 0.f, 0.f, 0.f};
                f32x4 s1 = f32x4{0.f, 0.f, 0.f, 0.f};
                __builtin_amdgcn_s_setprio(1);
                #pragma unroll
                for (int kc = 0; kc < 4; ++kc) {
                    bf16x8 vA = __builtin_bit_cast(bf16x8,
                        *(const ushort8*)(bufA + (nt * 4 + kc) * 512 + lane * 8));
                    s0 = __builtin_amdgcn_mfma_f32_16x16x32_bf16(vA, qf[0][kc], s0, 0, 0, 0);
                    s1 = __builtin_amdgcn_mfma_f32_16x16x32_bf16(vA, qf[1][kc], s1, 0, 0, 0);
                }
                __builtin_amdgcn_s_setprio(0);
                // exp2 + pack: k-slot quad*8 + (h? 4:0) + r  <->  t = nt*16+quad*4+r
                {
                    float p0 = __builtin_amdgcn_exp2f(s0[0]);
                    float p1 = __builtin_amdgcn_exp2f(s0[1]);
                    float p2 = __builtin_amdgcn_exp2f(s0[2]);
                    float p3 = __builtin_amdgcn_exp2f(s0[3]);
                    lsum[0] += (p0 + p1) + (p2 + p3);
                    pk[0][h * 2 + 0] = bfpack2(p0, p1);
                    pk[0][h * 2 + 1] = bfpack2(p2, p3);
                }
                {
                    float p0 = __builtin_amdgcn_exp2f(s1[0]);
                    float p1 = __builtin_amdgcn_exp2f(s1[1]);
                    float p2 = __builtin_amdgcn_exp2f(s1[2]);
                    float p3 = __builtin_amdgcn_exp2f(s1[3]);
                    lsum[1] += (p0 + p1) + (p2 + p3);
                    pk[1][h * 2 + 0] = bfpack2(p0, p1);
                    pk[1][h * 2 + 1] = bfpack2(p2, p3);
                }
            }

            if (a == 0) {
                // ---- barrier M: Vc(it) landed; QK(a=0) done with its bufA half
                asm volatile("s_waitcnt vmcnt(0)" ::: "memory");
                __builtin_amdgcn_s_barrier();
            } else {
                // ---- barrier E: all QK(a=1) bufA reads done across waves ----
                asm volatile("s_waitcnt lgkmcnt(0)" ::: "memory");
                __builtin_amdgcn_s_barrier();
                if (it + 1 < titers) issueA(Tbase + it + 1);  // PV(a=1) to land
            }

            // ---- PV sub-phase (K=32, k-permuted): D[m=q][n=c] ----
            bf16x8 pa0 = __builtin_bit_cast(bf16x8, pk[0]);
            bf16x8 pa1 = __builtin_bit_cast(bf16x8, pk[1]);
            __builtin_amdgcn_s_setprio(1);
            #pragma unroll
            for (int nc = 0; nc < 8; ++nc) {
                bf16x8 vB = __builtin_bit_cast(bf16x8,
                    *(const ushort8*)(bufB + (a * 8 + nc) * 512 + lane * 8));
                oacc[0][nc] = __builtin_amdgcn_mfma_f32_16x16x32_bf16(pa0, vB, oacc[0][nc], 0, 0, 0);
                oacc[1][nc] = __builtin_amdgcn_mfma_f32_16x16x32_bf16(pa1, vB, oacc[1][nc], 0, 0, 0);
            }
            __builtin_amdgcn_s_setprio(0);
        }
    }
    // ---- Lsum: per-lane partial (q=l16), reduce across the 4 quads ----
    const size_t pbase = ((size_t)(chunk * NB + b) * LQ);
    #pragma unroll
    for (int mt = 0; mt < 2; ++mt) {
        float v = lsum[mt];
        v += __shfl_xor(v, 16);
        v += __shfl_xor(v, 32);
        if (lane < 16) Lsum[pbase + q0w + mt * 16 + lane] = v;
    }
    // ---- partials: Opart[ch][b][q][c] (bf16); oacc lane: q=quad*4+r, c=l16
    #pragma unroll
    for (int mt = 0; mt < 2; ++mt)
        #pragma unroll
        for (int r = 0; r < 4; ++r) {
            const int q = q0w + mt * 16 + quad * 4 + r;
            unsigned short* orow = Opart + (pbase + q) * CH + l16;
            #pragma unroll
            for (int nc = 0; nc < 8; ++nc) orow[nc * 16] = f2bf(oacc[mt][nc][r]);
        }
}

// ---------------------------------------------------------------------------
// Kernel 3: out[b][c][q] = sum_ch Opart[ch][b][q][c] / sum_ch Lsum[ch][b][q]
// 512 blocks: (b, 32-q tile). LDS transpose.
// ---------------------------------------------------------------------------
__global__ __launch_bounds__(256) void combine_kernel(
    const unsigned short* __restrict__ Opart, const float* __restrict__ Lsum,
    float* __restrict__ out, int nchunk)
{
    __shared__ __align__(16) float ls[32 * 132];   // [q][c] padded
    __shared__ float linv[32];
    const int tid = threadIdx.x;
    const int b = blockIdx.x & 3;
    const int q0 = (blockIdx.x >> 2) << 5;

    if (tid < 32) {
        float s = 0.f;
        for (int ch = 0; ch < nchunk; ++ch) s += Lsum[(size_t)(ch * NB + b) * LQ + q0 + tid];
        linv[tid] = 1.0f / s;
    }
    __syncthreads();
    {
        const int c8 = (tid & 15) * 8, qg = tid >> 4;   // 16 q-groups x 2 q
        #pragma unroll
        for (int i = 0; i < 2; ++i) {
            const int q = qg * 2 + i;
            float s[8];
            #pragma unroll
            for (int k = 0; k < 8; ++k) s[k] = 0.f;
            for (int ch = 0; ch < nchunk; ++ch) {
                ushort8 p = *(const ushort8*)(Opart +
                    ((size_t)(ch * NB + b) * LQ + q0 + q) * CH + c8);
                #pragma unroll
                for (int k = 0; k < 8; ++k) s[k] += bf2f(p[k]);
            }
            const float li = linv[q];
            f32x4 o0, o1;
            #pragma unroll
            for (int k = 0; k < 4; ++k) { o0[k] = s[k] * li; o1[k] = s[k + 4] * li; }
            *(f32x4*)(ls + q * 132 + c8) = o0;
            *(f32x4*)(ls + q * 132 + c8 + 4) = o1;
        }
    }
    __syncthreads();
    {
        const int c = tid & 127, qh = tid >> 7;   // 2 halves of 16 q
        float* dst = out + ((size_t)b * CH + c) * LQ + q0 + qh * 16;
        #pragma unroll
        for (int i = 0; i < 4; ++i) {
            f32x4 o;
            #pragma unroll
            for (int r = 0; r < 4; ++r) o[r] = ls[(qh * 16 + i * 4 + r) * 132 + c];
            ((f32x4*)dst)[i] = o;
        }
    }
}

extern "C" void kernel_launch(void* const* d_in, const int* in_sizes, int n_in,
                              void* d_out, int out_size, void* d_ws, size_t ws_size,
                              hipStream_t stream) {
    const float* x   = (const float*)d_in[0];
    const float* Wkv = (const float*)d_in[1];
    const float* bkv = (const float*)d_in[2];
    float* out = (float*)d_out;

    const size_t vElems = (size_t)NB * LQ * CH;                 // 2M
    unsigned short* Vt2 = (unsigned short*)d_ws;                // 4 MB (tiled slots)
    unsigned short* Vc2 = Vt2 + vElems;                         // 4 MB (tiled slots)
    float* Lsum = (float*)(Vc2 + vElems);                       // 512 KB (MAXCH)
    unsigned short* Opart = (unsigned short*)(Lsum + (size_t)MAXCH * NB * LQ);

    // nchunk=8 -> attn grid 1024 = exactly 4 blocks/CU (32 KB LDS, 128-reg
    // budget via launch_bounds(256,4)). Falls back if workspace is short.
    int nchunk = 8;
    const size_t fixed = 2 * vElems * 2 + (size_t)MAXCH * NB * LQ * 4;
    while (nchunk > 1 && fixed + (size_t)nchunk * NB * LQ * CH * 2 > ws_size) nchunk >>= 1;
    const int titers = (LQ / 64) / nchunk;

    prep_kernel<<<dim3(256), dim3(256), 0, stream>>>(x, Wkv, bkv, Vt2, Vc2);
    attn_kernel<<<dim3(128 * nchunk), dim3(256), 0, stream>>>(x, Vt2, Vc2, Opart, Lsum, titers);
    combine_kernel<<<dim3(512), dim3(256), 0, stream>>>(Opart, Lsum, out, nchunk);
}

// Round 4
// 174.399 us; speedup vs baseline: 1.3957x; 1.3957x over previous
//
#include <hip/hip_runtime.h>

#define LQ 4096
#define CH 128
#define NB 4
// log2(e)/sqrt(128): folded into Q so softmax = exp2(S)
#define QSCALE 0.12753139626233174f
#define MAXCH 8
#define TILE_HW 8192   // one 64-key tile in fragment-slot order: 16 KB = 8192 ushort

typedef __attribute__((ext_vector_type(8))) unsigned short ushort8;
typedef __attribute__((ext_vector_type(4))) unsigned short ushort4v;
typedef __attribute__((ext_vector_type(8))) __bf16 bf16x8;
typedef __attribute__((ext_vector_type(4))) float f32x4;

__device__ inline unsigned short f2bf(float f) {
    unsigned int u = __builtin_bit_cast(unsigned int, f);
    u += 0x7fffu + ((u >> 16) & 1u);   // round-to-nearest-even
    return (unsigned short)(u >> 16);
}
__device__ inline float bf2f(unsigned short h) {
    unsigned int u = (unsigned int)h << 16;
    return __builtin_bit_cast(float, u);
}
// pack two positive floats to bf16 pair, round-half-up
__device__ inline unsigned int bfpack2(float a, float b) {
    unsigned int ua = __builtin_bit_cast(unsigned int, a) + 0x8000u;
    unsigned int ub = __builtin_bit_cast(unsigned int, b) + 0x8000u;
    return (ua >> 16) | (ub & 0xffff0000u);
}
// async 16B/lane global->LDS DMA: dest = lds_base + lane*16 (wave-uniform base)
__device__ inline void gload_lds16(const unsigned short* g, unsigned short* l) {
    __builtin_amdgcn_global_load_lds(
        (const __attribute__((address_space(1))) unsigned int*)(g),
        (__attribute__((address_space(3))) unsigned int*)(l), 16, 0, 0);
}

// ---------------------------------------------------------------------------
// Kernel 1: v = W_kv @ x (+bias), MFMA; emit Vt2/Vc2 in FRAGMENT-SLOT order
// (64-key tiles):
//   Vt2[b][T][g=nt*4+kc][lane=quad*16+l16] (16B) = V[t=64T+16nt+l16][c=32kc+8quad..+8]
//   Vc2[b][T][g=a*8+nc ][lane]             (16B):
//       element j = V[t = 32a + 16*(j>>2) + 4*quad + (j&3)][c = nc*16 + l16]
//   (k-permuted K=32 B-operand for PV: k-slot quad*8+j <-> t as above, matching
//    the S^T lane layout so P needs NO cross-lane shuffle to become the A-frag;
//    r12-verified numerically)
// ---------------------------------------------------------------------------
__global__ __launch_bounds__(256) void prep_kernel(
    const float* __restrict__ x, const float* __restrict__ Wkv,
    const float* __restrict__ bkv,
    unsigned short* __restrict__ Vt2, unsigned short* __restrict__ Vc2)
{
    __shared__ __align__(16) unsigned short xs[64 * 136];  // [l][c] bf16
    __shared__ __align__(16) unsigned short vs[128 * 72];  // [o][l] bf16
    const int tid = threadIdx.x;
    const int lane = tid & 63;
    const int wave = tid >> 6;
    const int quad = lane >> 4, l16 = lane & 15;
    const int b = blockIdx.x & 3;
    const int T = blockIdx.x >> 2;
    const int l0 = T << 6;

    {   // stage x tile transposed: [64 l][128 c] bf16 (coalesced f32x4 loads)
        const f32x4* xg4 = (const f32x4*)(x + (size_t)b * CH * LQ + l0);
        #pragma unroll
        for (int i = 0; i < 8; ++i) {
            int idx = i * 256 + tid;          // 2048 chunks: c(128) x l4(16)
            int c = idx >> 4, l4 = idx & 15;
            f32x4 v = xg4[c * (LQ / 4) + l4];
            #pragma unroll
            for (int m = 0; m < 4; ++m) xs[(l4 * 4 + m) * 136 + c] = f2bf(v[m]);
        }
    }
    __syncthreads();

    const int wo = wave * 32;
    f32x4 acc[2][4];   // [ot][lt]
    #pragma unroll
    for (int ot = 0; ot < 2; ++ot)
        #pragma unroll
        for (int lt = 0; lt < 4; ++lt) acc[ot][lt] = f32x4{0.f, 0.f, 0.f, 0.f};

    #pragma unroll
    for (int kc = 0; kc < 4; ++kc) {
        bf16x8 af[2];
        #pragma unroll
        for (int ot = 0; ot < 2; ++ot) {
            const float* wrow = Wkv + (size_t)(wo + ot * 16 + l16) * CH + kc * 32 + quad * 8;
            f32x4 w0 = *(const f32x4*)(wrow);
            f32x4 w1 = *(const f32x4*)(wrow + 4);
            ushort8 a;
            #pragma unroll
            for (int j = 0; j < 4; ++j) { a[j] = f2bf(w0[j]); a[j + 4] = f2bf(w1[j]); }
            af[ot] = __builtin_bit_cast(bf16x8, a);
        }
        #pragma unroll
        for (int lt = 0; lt < 4; ++lt) {
            bf16x8 bf = __builtin_bit_cast(bf16x8,
                *(const ushort8*)(xs + (lt * 16 + l16) * 136 + kc * 32 + quad * 8));
            #pragma unroll
            for (int ot = 0; ot < 2; ++ot)
                acc[ot][lt] = __builtin_amdgcn_mfma_f32_16x16x32_bf16(af[ot], bf, acc[ot][lt], 0, 0, 0);
        }
    }
    // bias + stage to vs[o][l] (C-layout: o = wo+ot*16+quad*4+r, l = lt*16+l16)
    #pragma unroll
    for (int ot = 0; ot < 2; ++ot) {
        float bias[4];
        #pragma unroll
        for (int r = 0; r < 4; ++r) bias[r] = bkv[wo + ot * 16 + quad * 4 + r];
        #pragma unroll
        for (int lt = 0; lt < 4; ++lt)
            #pragma unroll
            for (int r = 0; r < 4; ++r)
                vs[(wo + ot * 16 + quad * 4 + r) * 72 + lt * 16 + l16] =
                    f2bf(acc[ot][lt][r] + bias[r]);
    }
    __syncthreads();
    const size_t tbase = ((size_t)b * 64 + T) * TILE_HW;
    // Vt2: 1024 16B-chunks, 4/thread, consecutive tid -> consecutive 16B (coalesced)
    #pragma unroll
    for (int i = 0; i < 4; ++i) {
        const int ci = i * 256 + tid;
        const int g = ci >> 6, ls = ci & 63;
        const int nt = g >> 2, kc = g & 3, qs = ls >> 4, l16s = ls & 15;
        ushort8 v;
        #pragma unroll
        for (int j = 0; j < 8; ++j) v[j] = vs[(kc * 32 + qs * 8 + j) * 72 + nt * 16 + l16s];
        *(ushort8*)(Vt2 + tbase + (size_t)ci * 8) = v;
    }
    // Vc2: 1024 16B-chunks, K=32 k-permuted layout (see header comment)
    #pragma unroll
    for (int i = 0; i < 4; ++i) {
        const int ci = i * 256 + tid;
        const int g = ci >> 6, ls = ci & 63;
        const int a = g >> 3, nc = g & 7, qs = ls >> 4, l16s = ls & 15;
        const int base = (nc * 16 + l16s) * 72 + a * 32 + qs * 4;
        ushort4v lo4 = *(const ushort4v*)(vs + base);        // t = 32a+4q+0..3
        ushort4v hi4 = *(const ushort4v*)(vs + base + 16);   // t = 32a+16+4q+0..3
        ushort8 v;
        #pragma unroll
        for (int j = 0; j < 4; ++j) { v[j] = lo4[j]; v[j + 4] = hi4[j]; }
        *(ushort8*)(Vc2 + tbase + (size_t)ci * 8) = v;
    }
}

// ---------------------------------------------------------------------------
// Kernel 2: flash attention, split-K. r13 structure:
//   - Wave owns 64 q (mt=0..3): same 32 KB LDS-read per iter now covers 2x
//     the FLOPs -> LDS pipe work halves vs r11 (the serial-sum's biggest term).
//   - Registers: qf 64 + pk 16 + misc VGPR (~110) + oacc 128 AGPR ~= 240.
//     launch_bounds(256,2) caps at 256 -> NO forced spill (r12 lesson: the
//     state does not fit 128; 2 waves/SIMD is the operating point).
//   - Single-buffered bufA/bufB (32 KB), r12's race-free 3-barrier schedule:
//       [vmcnt0+bar] issueB -> QK(a=0) -> [vmcnt0+bar] PV(a=0) -> QK(a=1)
//       -> [lgkm0+bar] issueA(it+1) -> PV(a=1)
//   - PV uses K=32 MFMA with k-permuted Vc2 (r12-verified): 64+64 MFMA/iter.
//   - Grid: 256 q/block -> 64 blocks/chunk; nchunk=8 -> 512 blocks = 2/CU
//     (two independent barrier domains per CU -> phase slip -> pipe overlap).
// Every LDS read is ds_read_b128 at group_base + lane*16 (conflict-free).
// ---------------------------------------------------------------------------
__global__ __launch_bounds__(256, 2) void attn_kernel(
    const float* __restrict__ x, const unsigned short* __restrict__ Vt2,
    const unsigned short* __restrict__ Vc2,
    unsigned short* __restrict__ Opart, float* __restrict__ Lsum, int titers)
{
    __shared__ __align__(16) unsigned short bufA[TILE_HW];  // Vt tile, 16 KB
    __shared__ __align__(16) unsigned short bufB[TILE_HW];  // Vc tile, 16 KB
    const int tid = threadIdx.x;
    const int wave = tid >> 6, lane = tid & 63;
    const int quad = lane >> 4, l16 = lane & 15;
    const int b = blockIdx.x & 3;
    const int rest = blockIdx.x >> 2;
    const int qtile = rest & 15;           // 16 tiles of 256 q
    const int chunk = rest >> 4;           // nchunk split-K chunks
    const int q0w = (qtile << 8) + (wave << 6);   // wave owns 64 q
    const int Tbase = chunk * titers;

    const unsigned short* vtb = Vt2 + (size_t)b * 64 * TILE_HW;
    const unsigned short* vcb = Vc2 + (size_t)b * 64 * TILE_HW;

    // DMA issue: wave w stages groups w*4..w*4+3 of one tensor (4 instr/wave)
    auto issueA = [&](int T) {
        const unsigned short* sa = vtb + (size_t)T * TILE_HW + lane * 8;
        #pragma unroll
        for (int g = 0; g < 4; ++g) {
            const int go = (wave * 4 + g) * 512;
            gload_lds16(sa + go, &bufA[go]);
        }
    };
    auto issueB = [&](int T) {
        const unsigned short* sb = vcb + (size_t)T * TILE_HW + lane * 8;
        #pragma unroll
        for (int g = 0; g < 4; ++g) {
            const int go = (wave * 4 + g) * 512;
            gload_lds16(sb + go, &bufB[go]);
        }
    };
    issueA(Tbase);   // in flight under the Q prologue

    // Q B-frags from x: B[n=l16 -> q][k=quad*8+j -> c], scaled (one-time)
    bf16x8 qf[4][4];
    #pragma unroll
    for (int mt = 0; mt < 4; ++mt)
        #pragma unroll
        for (int kc = 0; kc < 4; ++kc) {
            ushort8 v;
            #pragma unroll
            for (int j = 0; j < 8; ++j) {
                int c = kc * 32 + quad * 8 + j;
                v[j] = f2bf(x[((size_t)b * CH + c) * LQ + q0w + mt * 16 + l16] * QSCALE);
            }
            qf[mt][kc] = __builtin_bit_cast(bf16x8, v);
        }

    f32x4 oacc[4][8];
    #pragma unroll
    for (int mt = 0; mt < 4; ++mt)
        #pragma unroll
        for (int i = 0; i < 8; ++i) oacc[mt][i] = f32x4{0.f, 0.f, 0.f, 0.f};
    float lsum[4] = {0.f, 0.f, 0.f, 0.f};

    for (int it = 0; it < titers; ++it) {
        // ---- barrier A: Vt(it) landed; prior PV(a=1) bufB reads done ----
        asm volatile("s_waitcnt vmcnt(0)" ::: "memory");
        __builtin_amdgcn_s_barrier();
        issueB(Tbase + it);        // Vc(it): QK(a=0) phase to land

        unsigned int pk[4][4];     // P as K=32 A-frag words (16 VGPR)

        #pragma unroll
        for (int a = 0; a < 2; ++a) {
            // ---- QK sub-phase: nt = 2a, 2a+1 -> pk ----
            #pragma unroll
            for (int h = 0; h < 2; ++h) {
                const int nt = a * 2 + h;
                // V A-frags: conflict-free b128 at group base + lane*16
                bf16x8 vA[4];
                #pragma unroll
                for (int kc = 0; kc < 4; ++kc)
                    vA[kc] = __builtin_bit_cast(bf16x8,
                        *(const ushort8*)(bufA + (nt * 4 + kc) * 512 + lane * 8));
                // S^T: D[m=t][n=q]; lane: q=l16, t=nt*16+quad*4+r
                f32x4 s[4];
                #pragma unroll
                for (int mt = 0; mt < 4; ++mt) s[mt] = f32x4{0.f, 0.f, 0.f, 0.f};
                __builtin_amdgcn_s_setprio(1);
                #pragma unroll
                for (int kc = 0; kc < 4; ++kc)
                    #pragma unroll
                    for (int mt = 0; mt < 4; ++mt)
                        s[mt] = __builtin_amdgcn_mfma_f32_16x16x32_bf16(vA[kc], qf[mt][kc], s[mt], 0, 0, 0);
                __builtin_amdgcn_s_setprio(0);
                // exp2 + pack: k-slot quad*8 + h*4 + r  <->  t = nt*16+quad*4+r
                #pragma unroll
                for (int mt = 0; mt < 4; ++mt) {
                    float p0 = __builtin_amdgcn_exp2f(s[mt][0]);
                    float p1 = __builtin_amdgcn_exp2f(s[mt][1]);
                    float p2 = __builtin_amdgcn_exp2f(s[mt][2]);
                    float p3 = __builtin_amdgcn_exp2f(s[mt][3]);
                    lsum[mt] += (p0 + p1) + (p2 + p3);
                    pk[mt][h * 2 + 0] = bfpack2(p0, p1);
                    pk[mt][h * 2 + 1] = bfpack2(p2, p3);
                }
            }

            if (a == 0) {
                // ---- barrier M: Vc(it) landed; PV(a=0) may read bufB ----
                asm volatile("s_waitcnt vmcnt(0)" ::: "memory");
                __builtin_amdgcn_s_barrier();
            } else {
                // ---- barrier E: all QK bufA reads done across waves ----
                asm volatile("s_waitcnt lgkmcnt(0)" ::: "memory");
                __builtin_amdgcn_s_barrier();
                if (it + 1 < titers) issueA(Tbase + it + 1);  // PV(a=1) to land
            }

            // ---- PV sub-phase (K=32, k-permuted): D[m=q][n=c] ----
            bf16x8 pa[4];
            #pragma unroll
            for (int mt = 0; mt < 4; ++mt)
                pa[mt] = __builtin_bit_cast(bf16x8, pk[mt]);
            __builtin_amdgcn_s_setprio(1);
            #pragma unroll
            for (int nc = 0; nc < 8; ++nc) {
                bf16x8 vB = __builtin_bit_cast(bf16x8,
                    *(const ushort8*)(bufB + (a * 8 + nc) * 512 + lane * 8));
                #pragma unroll
                for (int mt = 0; mt < 4; ++mt)
                    oacc[mt][nc] = __builtin_amdgcn_mfma_f32_16x16x32_bf16(pa[mt], vB, oacc[mt][nc], 0, 0, 0);
            }
            __builtin_amdgcn_s_setprio(0);
        }
    }
    // ---- Lsum: per-lane partial (q=l16), reduce across the 4 quads ----
    const size_t pbase = ((size_t)(chunk * NB + b) * LQ);
    #pragma unroll
    for (int mt = 0; mt < 4; ++mt) {
        float v = lsum[mt];
        v += __shfl_xor(v, 16);
        v += __shfl_xor(v, 32);
        if (lane < 16) Lsum[pbase + q0w + mt * 16 + lane] = v;
    }
    // ---- partials: Opart[ch][b][q][c] (bf16); oacc lane: q=quad*4+r, c=l16
    #pragma unroll
    for (int mt = 0; mt < 4; ++mt)
        #pragma unroll
        for (int r = 0; r < 4; ++r) {
            const int q = q0w + mt * 16 + quad * 4 + r;
            unsigned short* orow = Opart + (pbase + q) * CH + l16;
            #pragma unroll
            for (int nc = 0; nc < 8; ++nc) orow[nc * 16] = f2bf(oacc[mt][nc][r]);
        }
}

// ---------------------------------------------------------------------------
// Kernel 3: out[b][c][q] = sum_ch Opart[ch][b][q][c] / sum_ch Lsum[ch][b][q]
// 512 blocks: (b, 32-q tile). LDS transpose.
// ---------------------------------------------------------------------------
__global__ __launch_bounds__(256) void combine_kernel(
    const unsigned short* __restrict__ Opart, const float* __restrict__ Lsum,
    float* __restrict__ out, int nchunk)
{
    __shared__ __align__(16) float ls[32 * 132];   // [q][c] padded
    __shared__ float linv[32];
    const int tid = threadIdx.x;
    const int b = blockIdx.x & 3;
    const int q0 = (blockIdx.x >> 2) << 5;

    if (tid < 32) {
        float s = 0.f;
        for (int ch = 0; ch < nchunk; ++ch) s += Lsum[(size_t)(ch * NB + b) * LQ + q0 + tid];
        linv[tid] = 1.0f / s;
    }
    __syncthreads();
    {
        const int c8 = (tid & 15) * 8, qg = tid >> 4;   // 16 q-groups x 2 q
        #pragma unroll
        for (int i = 0; i < 2; ++i) {
            const int q = qg * 2 + i;
            float s[8];
            #pragma unroll
            for (int k = 0; k < 8; ++k) s[k] = 0.f;
            for (int ch = 0; ch < nchunk; ++ch) {
                ushort8 p = *(const ushort8*)(Opart +
                    ((size_t)(ch * NB + b) * LQ + q0 + q) * CH + c8);
                #pragma unroll
                for (int k = 0; k < 8; ++k) s[k] += bf2f(p[k]);
            }
            const float li = linv[q];
            f32x4 o0, o1;
            #pragma unroll
            for (int k = 0; k < 4; ++k) { o0[k] = s[k] * li; o1[k] = s[k + 4] * li; }
            *(f32x4*)(ls + q * 132 + c8) = o0;
            *(f32x4*)(ls + q * 132 + c8 + 4) = o1;
        }
    }
    __syncthreads();
    {
        const int c = tid & 127, qh = tid >> 7;   // 2 halves of 16 q
        float* dst = out + ((size_t)b * CH + c) * LQ + q0 + qh * 16;
        #pragma unroll
        for (int i = 0; i < 4; ++i) {
            f32x4 o;
            #pragma unroll
            for (int r = 0; r < 4; ++r) o[r] = ls[(qh * 16 + i * 4 + r) * 132 + c];
            ((f32x4*)dst)[i] = o;
        }
    }
}

extern "C" void kernel_launch(void* const* d_in, const int* in_sizes, int n_in,
                              void* d_out, int out_size, void* d_ws, size_t ws_size,
                              hipStream_t stream) {
    const float* x   = (const float*)d_in[0];
    const float* Wkv = (const float*)d_in[1];
    const float* bkv = (const float*)d_in[2];
    float* out = (float*)d_out;

    const size_t vElems = (size_t)NB * LQ * CH;                 // 2M
    unsigned short* Vt2 = (unsigned short*)d_ws;                // 4 MB (tiled slots)
    unsigned short* Vc2 = Vt2 + vElems;                         // 4 MB (tiled slots)
    float* Lsum = (float*)(Vc2 + vElems);                       // 512 KB (MAXCH)
    unsigned short* Opart = (unsigned short*)(Lsum + (size_t)MAXCH * NB * LQ);

    // nchunk=8 -> attn grid 512 = 2 blocks/CU (32 KB LDS, 2 waves/SIMD).
    // Falls back if workspace is short.
    int nchunk = 8;
    const size_t fixed = 2 * vElems * 2 + (size_t)MAXCH * NB * LQ * 4;
    while (nchunk > 1 && fixed + (size_t)nchunk * NB * LQ * CH * 2 > ws_size) nchunk >>= 1;
    const int titers = (LQ / 64) / nchunk;

    prep_kernel<<<dim3(256), dim3(256), 0, stream>>>(x, Wkv, bkv, Vt2, Vc2);
    attn_kernel<<<dim3(64 * nchunk), dim3(256), 0, stream>>>(x, Vt2, Vc2, Opart, Lsum, titers);
    combine_kernel<<<dim3(512), dim3(256), 0, stream>>>(Opart, Lsum, out, nchunk);
}

// Round 5
// 116.417 us; speedup vs baseline: 2.0908x; 1.4981x over previous
//
#include <hip/hip_runtime.h>

#define LQ 4096
#define CH 128
#define NB 4
// log2(e)/sqrt(128): folded into Q so softmax = exp2(S)
#define QSCALE 0.12753139626233174f
#define MAXCH 8
#define TILE_HW 8192   // one 64-key tile in fragment-slot order: 16 KB = 8192 ushort

typedef __attribute__((ext_vector_type(8))) unsigned short ushort8;
typedef __attribute__((ext_vector_type(4))) unsigned short ushort4v;
typedef __attribute__((ext_vector_type(4))) unsigned int uint32x4;
typedef __attribute__((ext_vector_type(8))) __bf16 bf16x8;
typedef __attribute__((ext_vector_type(4))) float f32x4;

__device__ inline unsigned short f2bf(float f) {
    unsigned int u = __builtin_bit_cast(unsigned int, f);
    u += 0x7fffu + ((u >> 16) & 1u);   // round-to-nearest-even
    return (unsigned short)(u >> 16);
}
__device__ inline float bf2f(unsigned short h) {
    unsigned int u = (unsigned int)h << 16;
    return __builtin_bit_cast(float, u);
}
// pack two positive floats to bf16 pair, round-half-up
__device__ inline unsigned int bfpack2(float a, float b) {
    unsigned int ua = __builtin_bit_cast(unsigned int, a) + 0x8000u;
    unsigned int ub = __builtin_bit_cast(unsigned int, b) + 0x8000u;
    return (ua >> 16) | (ub & 0xffff0000u);
}
// async 16B/lane global->LDS DMA: dest = lds_base + lane*16 (wave-uniform base)
__device__ inline void gload_lds16(const unsigned short* g, unsigned short* l) {
    __builtin_amdgcn_global_load_lds(
        (const __attribute__((address_space(1))) unsigned int*)(g),
        (__attribute__((address_space(3))) unsigned int*)(l), 16, 0, 0);
}

// ---------------------------------------------------------------------------
// Kernel 1: v = W_kv @ x (+bias), MFMA; emit Vt2/Vc2 in FRAGMENT-SLOT order
// (64-key tiles):
//   Vt2[b][T][g=nt*4+kc][lane=quad*16+l16] (16B) = V[t=64T+16nt+l16][c=32kc+8quad..+8]
//   Vc2[b][T][g=a*8+nc ][lane]             (16B):
//       element j = V[t = 32a + 16*(j>>2) + 4*quad + (j&3)][c = nc*16 + l16]
//   (k-permuted K=32 B-operand for PV: k-slot quad*8+j <-> t as above, matching
//    the S^T lane layout so P needs NO cross-lane shuffle to become the A-frag;
//    numerically verified in r12 AND r13)
// ---------------------------------------------------------------------------
__global__ __launch_bounds__(256) void prep_kernel(
    const float* __restrict__ x, const float* __restrict__ Wkv,
    const float* __restrict__ bkv,
    unsigned short* __restrict__ Vt2, unsigned short* __restrict__ Vc2)
{
    __shared__ __align__(16) unsigned short xs[64 * 136];  // [l][c] bf16
    __shared__ __align__(16) unsigned short vs[128 * 72];  // [o][l] bf16
    const int tid = threadIdx.x;
    const int lane = tid & 63;
    const int wave = tid >> 6;
    const int quad = lane >> 4, l16 = lane & 15;
    const int b = blockIdx.x & 3;
    const int T = blockIdx.x >> 2;
    const int l0 = T << 6;

    {   // stage x tile transposed: [64 l][128 c] bf16 (coalesced f32x4 loads)
        const f32x4* xg4 = (const f32x4*)(x + (size_t)b * CH * LQ + l0);
        #pragma unroll
        for (int i = 0; i < 8; ++i) {
            int idx = i * 256 + tid;          // 2048 chunks: c(128) x l4(16)
            int c = idx >> 4, l4 = idx & 15;
            f32x4 v = xg4[c * (LQ / 4) + l4];
            #pragma unroll
            for (int m = 0; m < 4; ++m) xs[(l4 * 4 + m) * 136 + c] = f2bf(v[m]);
        }
    }
    __syncthreads();

    const int wo = wave * 32;
    f32x4 acc[2][4];   // [ot][lt]
    #pragma unroll
    for (int ot = 0; ot < 2; ++ot)
        #pragma unroll
        for (int lt = 0; lt < 4; ++lt) acc[ot][lt] = f32x4{0.f, 0.f, 0.f, 0.f};

    #pragma unroll
    for (int kc = 0; kc < 4; ++kc) {
        bf16x8 af[2];
        #pragma unroll
        for (int ot = 0; ot < 2; ++ot) {
            const float* wrow = Wkv + (size_t)(wo + ot * 16 + l16) * CH + kc * 32 + quad * 8;
            f32x4 w0 = *(const f32x4*)(wrow);
            f32x4 w1 = *(const f32x4*)(wrow + 4);
            ushort8 a;
            #pragma unroll
            for (int j = 0; j < 4; ++j) { a[j] = f2bf(w0[j]); a[j + 4] = f2bf(w1[j]); }
            af[ot] = __builtin_bit_cast(bf16x8, a);
        }
        #pragma unroll
        for (int lt = 0; lt < 4; ++lt) {
            bf16x8 bf = __builtin_bit_cast(bf16x8,
                *(const ushort8*)(xs + (lt * 16 + l16) * 136 + kc * 32 + quad * 8));
            #pragma unroll
            for (int ot = 0; ot < 2; ++ot)
                acc[ot][lt] = __builtin_amdgcn_mfma_f32_16x16x32_bf16(af[ot], bf, acc[ot][lt], 0, 0, 0);
        }
    }
    // bias + stage to vs[o][l] (C-layout: o = wo+ot*16+quad*4+r, l = lt*16+l16)
    #pragma unroll
    for (int ot = 0; ot < 2; ++ot) {
        float bias[4];
        #pragma unroll
        for (int r = 0; r < 4; ++r) bias[r] = bkv[wo + ot * 16 + quad * 4 + r];
        #pragma unroll
        for (int lt = 0; lt < 4; ++lt)
            #pragma unroll
            for (int r = 0; r < 4; ++r)
                vs[(wo + ot * 16 + quad * 4 + r) * 72 + lt * 16 + l16] =
                    f2bf(acc[ot][lt][r] + bias[r]);
    }
    __syncthreads();
    const size_t tbase = ((size_t)b * 64 + T) * TILE_HW;
    // Vt2: 1024 16B-chunks, 4/thread, consecutive tid -> consecutive 16B (coalesced)
    #pragma unroll
    for (int i = 0; i < 4; ++i) {
        const int ci = i * 256 + tid;
        const int g = ci >> 6, ls = ci & 63;
        const int nt = g >> 2, kc = g & 3, qs = ls >> 4, l16s = ls & 15;
        ushort8 v;
        #pragma unroll
        for (int j = 0; j < 8; ++j) v[j] = vs[(kc * 32 + qs * 8 + j) * 72 + nt * 16 + l16s];
        *(ushort8*)(Vt2 + tbase + (size_t)ci * 8) = v;
    }
    // Vc2: 1024 16B-chunks, K=32 k-permuted layout (see header comment)
    #pragma unroll
    for (int i = 0; i < 4; ++i) {
        const int ci = i * 256 + tid;
        const int g = ci >> 6, ls = ci & 63;
        const int a = g >> 3, nc = g & 7, qs = ls >> 4, l16s = ls & 15;
        const int base = (nc * 16 + l16s) * 72 + a * 32 + qs * 4;
        ushort4v lo4 = *(const ushort4v*)(vs + base);        // t = 32a+4q+0..3
        ushort4v hi4 = *(const ushort4v*)(vs + base + 16);   // t = 32a+16+4q+0..3
        ushort8 v;
        #pragma unroll
        for (int j = 0; j < 4; ++j) { v[j] = lo4[j]; v[j + 4] = hi4[j]; }
        *(ushort8*)(Vc2 + tbase + (size_t)ci * 8) = v;
    }
}

// ---------------------------------------------------------------------------
// Kernel 2: flash attention, split-K. r14 = r11 (measured best, 51.6 us)
// with ONE change: PV uses K=32 MFMA via the k-permuted Vc2 (r12/r13-verified)
// -> 64 MFMA/iter/wave instead of 96 (PV matrix-pipe time halves).
//   - 32 q/wave (mt=2): the non-spilling operating point (r12/r13 lesson:
//     128- and 256-reg budgets both spill; ~158 total regs here fits 2
//     waves/SIMD with slack).
//   - 64-key tiles, SINGLE-buffered bufA/bufB (32 KB LDS), 2 barriers/iter:
//       [vmcnt0+bar] issueB -> QK all 4 nt -> [vmcnt0+lgkm0+bar]
//       issueA(it+1) -> PV (K=32, both halves)
//   - nchunk=4: r11's nchunk=8 cost more in combine (+4.4us) than it bought
//     in attn (-2.4us); residency is 2 blocks/CU either way.
// Every LDS read is ds_read_b128 at group_base + lane*16 (conflict-free).
// ---------------------------------------------------------------------------
__global__ __launch_bounds__(256, 2) void attn_kernel(
    const float* __restrict__ x, const unsigned short* __restrict__ Vt2,
    const unsigned short* __restrict__ Vc2,
    unsigned short* __restrict__ Opart, float* __restrict__ Lsum, int titers)
{
    __shared__ __align__(16) unsigned short bufA[TILE_HW];  // Vt tile, 16 KB
    __shared__ __align__(16) unsigned short bufB[TILE_HW];  // Vc tile, 16 KB
    const int tid = threadIdx.x;
    const int wave = tid >> 6, lane = tid & 63;
    const int quad = lane >> 4, l16 = lane & 15;
    const int b = blockIdx.x & 3;
    const int rest = blockIdx.x >> 2;
    const int qtile = rest & 31;           // 32 tiles of 128 q
    const int chunk = rest >> 5;           // nchunk split-K chunks
    const int q0w = (qtile << 7) + (wave << 5);
    const int Tbase = chunk * titers;

    const unsigned short* vtb = Vt2 + (size_t)b * 64 * TILE_HW;
    const unsigned short* vcb = Vc2 + (size_t)b * 64 * TILE_HW;

    // DMA issue: wave w stages groups w*4..w*4+3 of one tensor (4 instr/wave)
    auto issueA = [&](int T) {
        const unsigned short* sa = vtb + (size_t)T * TILE_HW + lane * 8;
        #pragma unroll
        for (int g = 0; g < 4; ++g) {
            const int go = (wave * 4 + g) * 512;
            gload_lds16(sa + go, &bufA[go]);
        }
    };
    auto issueB = [&](int T) {
        const unsigned short* sb = vcb + (size_t)T * TILE_HW + lane * 8;
        #pragma unroll
        for (int g = 0; g < 4; ++g) {
            const int go = (wave * 4 + g) * 512;
            gload_lds16(sb + go, &bufB[go]);
        }
    };
    issueA(Tbase);   // in flight under the Q prologue

    // Q B-frags from x: B[n=l16 -> q][k=quad*8+j -> c], scaled (one-time)
    bf16x8 qf[2][4];
    #pragma unroll
    for (int mt = 0; mt < 2; ++mt)
        #pragma unroll
        for (int kc = 0; kc < 4; ++kc) {
            ushort8 v;
            #pragma unroll
            for (int j = 0; j < 8; ++j) {
                int c = kc * 32 + quad * 8 + j;
                v[j] = f2bf(x[((size_t)b * CH + c) * LQ + q0w + mt * 16 + l16] * QSCALE);
            }
            qf[mt][kc] = __builtin_bit_cast(bf16x8, v);
        }

    f32x4 oacc[2][8];
    #pragma unroll
    for (int mt = 0; mt < 2; ++mt)
        #pragma unroll
        for (int i = 0; i < 8; ++i) oacc[mt][i] = f32x4{0.f, 0.f, 0.f, 0.f};
    float lsum[2] = {0.f, 0.f};

    for (int it = 0; it < titers; ++it) {
        // ---- barrier A: Vt(it) landed (own vmcnt0 + cross-wave via barrier);
        // all waves are past PV(it-1), so bufB may be overwritten.
        asm volatile("s_waitcnt vmcnt(0)" ::: "memory");
        __builtin_amdgcn_s_barrier();
        issueB(Tbase + it);        // Vc(it): full QK phase to land

        // P as K=32 A-frag words: pk[mt][a] covers keys t=32a..32a+31 with
        // k-slot (quad,j): t = 32a + 16*(j>>2) + 4*quad + (j&3)
        uint32x4 pk[2][2];

        // ---- QK phase: all 4 nt ----
        #pragma unroll
        for (int nt = 0; nt < 4; ++nt) {
            const int aIdx = nt >> 1, h = nt & 1;
            // V A-frags: conflict-free b128 at group base + lane*16
            bf16x8 vA[4];
            #pragma unroll
            for (int kc = 0; kc < 4; ++kc)
                vA[kc] = __builtin_bit_cast(bf16x8,
                    *(const ushort8*)(bufA + (nt * 4 + kc) * 512 + lane * 8));
            // S^T: D[m=t][n=q]; lane: q=l16, t=nt*16+quad*4+r
            f32x4 s[2];
            __builtin_amdgcn_s_setprio(1);
            #pragma unroll
            for (int mt = 0; mt < 2; ++mt) {
                s[mt] = f32x4{0.f, 0.f, 0.f, 0.f};
                #pragma unroll
                for (int kc = 0; kc < 4; ++kc)
                    s[mt] = __builtin_amdgcn_mfma_f32_16x16x32_bf16(vA[kc], qf[mt][kc], s[mt], 0, 0, 0);
            }
            __builtin_amdgcn_s_setprio(0);
            // exp2 + pack into the K=32 A-frag word slots
            #pragma unroll
            for (int mt = 0; mt < 2; ++mt) {
                float p0 = __builtin_amdgcn_exp2f(s[mt][0]);
                float p1 = __builtin_amdgcn_exp2f(s[mt][1]);
                float p2 = __builtin_amdgcn_exp2f(s[mt][2]);
                float p3 = __builtin_amdgcn_exp2f(s[mt][3]);
                lsum[mt] += (p0 + p1) + (p2 + p3);
                pk[mt][aIdx][h * 2 + 0] = bfpack2(p0, p1);
                pk[mt][aIdx][h * 2 + 1] = bfpack2(p2, p3);
            }
        }

        // ---- barrier M: Vc(it) landed; QK bufA reads done across waves
        // (lgkm0 makes the bufA-overwrite fence airtight) ----
        asm volatile("s_waitcnt vmcnt(0) lgkmcnt(0)" ::: "memory");
        __builtin_amdgcn_s_barrier();
        if (it + 1 < titers) issueA(Tbase + it + 1);  // full PV phase to land

        // ---- PV phase (K=32, k-permuted): D[m=q][n=c] ----
        __builtin_amdgcn_s_setprio(1);
        #pragma unroll
        for (int a = 0; a < 2; ++a) {
            bf16x8 pa0 = __builtin_bit_cast(bf16x8, pk[0][a]);
            bf16x8 pa1 = __builtin_bit_cast(bf16x8, pk[1][a]);
            #pragma unroll
            for (int nc = 0; nc < 8; ++nc) {
                bf16x8 vB = __builtin_bit_cast(bf16x8,
                    *(const ushort8*)(bufB + (a * 8 + nc) * 512 + lane * 8));
                oacc[0][nc] = __builtin_amdgcn_mfma_f32_16x16x32_bf16(pa0, vB, oacc[0][nc], 0, 0, 0);
                oacc[1][nc] = __builtin_amdgcn_mfma_f32_16x16x32_bf16(pa1, vB, oacc[1][nc], 0, 0, 0);
            }
        }
        __builtin_amdgcn_s_setprio(0);
    }
    // ---- Lsum: per-lane partial (q=l16), reduce across the 4 quads ----
    const size_t pbase = ((size_t)(chunk * NB + b) * LQ);
    #pragma unroll
    for (int mt = 0; mt < 2; ++mt) {
        float v = lsum[mt];
        v += __shfl_xor(v, 16);
        v += __shfl_xor(v, 32);
        if (lane < 16) Lsum[pbase + q0w + mt * 16 + lane] = v;
    }
    // ---- partials: Opart[ch][b][q][c] (bf16); oacc lane: q=quad*4+r, c=l16
    #pragma unroll
    for (int mt = 0; mt < 2; ++mt)
        #pragma unroll
        for (int r = 0; r < 4; ++r) {
            const int q = q0w + mt * 16 + quad * 4 + r;
            unsigned short* orow = Opart + (pbase + q) * CH + l16;
            #pragma unroll
            for (int nc = 0; nc < 8; ++nc) orow[nc * 16] = f2bf(oacc[mt][nc][r]);
        }
}

// ---------------------------------------------------------------------------
// Kernel 3: out[b][c][q] = sum_ch Opart[ch][b][q][c] / sum_ch Lsum[ch][b][q]
// 512 blocks: (b, 32-q tile). LDS transpose.
// ---------------------------------------------------------------------------
__global__ __launch_bounds__(256) void combine_kernel(
    const unsigned short* __restrict__ Opart, const float* __restrict__ Lsum,
    float* __restrict__ out, int nchunk)
{
    __shared__ __align__(16) float ls[32 * 132];   // [q][c] padded
    __shared__ float linv[32];
    const int tid = threadIdx.x;
    const int b = blockIdx.x & 3;
    const int q0 = (blockIdx.x >> 2) << 5;

    if (tid < 32) {
        float s = 0.f;
        for (int ch = 0; ch < nchunk; ++ch) s += Lsum[(size_t)(ch * NB + b) * LQ + q0 + tid];
        linv[tid] = 1.0f / s;
    }
    __syncthreads();
    {
        const int c8 = (tid & 15) * 8, qg = tid >> 4;   // 16 q-groups x 2 q
        #pragma unroll
        for (int i = 0; i < 2; ++i) {
            const int q = qg * 2 + i;
            float s[8];
            #pragma unroll
            for (int k = 0; k < 8; ++k) s[k] = 0.f;
            for (int ch = 0; ch < nchunk; ++ch) {
                ushort8 p = *(const ushort8*)(Opart +
                    ((size_t)(ch * NB + b) * LQ + q0 + q) * CH + c8);
                #pragma unroll
                for (int k = 0; k < 8; ++k) s[k] += bf2f(p[k]);
            }
            const float li = linv[q];
            f32x4 o0, o1;
            #pragma unroll
            for (int k = 0; k < 4; ++k) { o0[k] = s[k] * li; o1[k] = s[k + 4] * li; }
            *(f32x4*)(ls + q * 132 + c8) = o0;
            *(f32x4*)(ls + q * 132 + c8 + 4) = o1;
        }
    }
    __syncthreads();
    {
        const int c = tid & 127, qh = tid >> 7;   // 2 halves of 16 q
        float* dst = out + ((size_t)b * CH + c) * LQ + q0 + qh * 16;
        #pragma unroll
        for (int i = 0; i < 4; ++i) {
            f32x4 o;
            #pragma unroll
            for (int r = 0; r < 4; ++r) o[r] = ls[(qh * 16 + i * 4 + r) * 132 + c];
            ((f32x4*)dst)[i] = o;
        }
    }
}

extern "C" void kernel_launch(void* const* d_in, const int* in_sizes, int n_in,
                              void* d_out, int out_size, void* d_ws, size_t ws_size,
                              hipStream_t stream) {
    const float* x   = (const float*)d_in[0];
    const float* Wkv = (const float*)d_in[1];
    const float* bkv = (const float*)d_in[2];
    float* out = (float*)d_out;

    const size_t vElems = (size_t)NB * LQ * CH;                 // 2M
    unsigned short* Vt2 = (unsigned short*)d_ws;                // 4 MB (tiled slots)
    unsigned short* Vc2 = Vt2 + vElems;                         // 4 MB (tiled slots)
    float* Lsum = (float*)(Vc2 + vElems);                       // 512 KB (MAXCH)
    unsigned short* Opart = (unsigned short*)(Lsum + (size_t)MAXCH * NB * LQ);

    // nchunk=4 -> attn grid 512 = 2 blocks/CU; combine traffic minimal.
    int nchunk = 4;
    const size_t fixed = 2 * vElems * 2 + (size_t)MAXCH * NB * LQ * 4;
    while (nchunk > 1 && fixed + (size_t)nchunk * NB * LQ * CH * 2 > ws_size) nchunk >>= 1;
    const int titers = (LQ / 64) / nchunk;

    prep_kernel<<<dim3(256), dim3(256), 0, stream>>>(x, Wkv, bkv, Vt2, Vc2);
    attn_kernel<<<dim3(128 * nchunk), dim3(256), 0, stream>>>(x, Vt2, Vc2, Opart, Lsum, titers);
    combine_kernel<<<dim3(512), dim3(256), 0, stream>>>(Opart, Lsum, out, nchunk);
}